// Round 10
// baseline (3100.026 us; speedup 1.0000x reference)
//
#include <hip/hip_runtime.h>

typedef unsigned short u16;
typedef unsigned int   u32;
typedef unsigned long long u64;
typedef __bf16 bf16x8 __attribute__((ext_vector_type(8)));
typedef float  f32x4  __attribute__((ext_vector_type(4)));

#define AS1 __attribute__((address_space(1)))
#define AS3 __attribute__((address_space(3)))

#define M_TOK 8192
#define K_DIM 4096
#define N_DIM 4096
#define BK    32
#define NKT   (K_DIM / BK)   // 128

static __device__ __forceinline__ u16 f2bf(float f) {
  u32 u = __builtin_bit_cast(u32, f);
  return (u16)((u + (0x7FFFu + ((u >> 16) & 1u))) >> 16);
}

// global -> LDS direct copy, 16B per lane. LDS dest is wave-uniform base;
// HW stores lane l at dest + l*16 (linear, rule #21).
static __device__ __forceinline__ void gld_lds16(const void* g, void* l) {
  __builtin_amdgcn_global_load_lds((AS1 u32*)(u64)g, (AS3 u32*)(u32)(u64)l, 16, 0, 0);
}

// ---- fused prep: blocks [0, M_TOK) do per-token x->bf16 + LoRA mid;
//      blocks [M_TOK, M_TOK+2048) convert W_main f32->bf16 (grid-stride). ----
__global__ __launch_bounds__(256) void k_prep(const float* __restrict__ x,
                                              const float* __restrict__ WA,
                                              const float* __restrict__ W,
                                              u16* __restrict__ xb,
                                              float* __restrict__ mid,
                                              u16* __restrict__ Wb) {
  const int t = threadIdx.x;
  if (blockIdx.x >= M_TOK) {
    const int cb = blockIdx.x - M_TOK;           // 0..2047
    const float4* W4 = (const float4*)W;
    ushort4* Wb4 = (ushort4*)Wb;
    const int n4 = (N_DIM * K_DIM) / 4;
    int i = cb * 256 + t;
    for (; i < n4; i += 2048 * 256) {
      float4 v = W4[i];
      ushort4 o;
      o.x = f2bf(v.x); o.y = f2bf(v.y); o.z = f2bf(v.z); o.w = f2bf(v.w);
      Wb4[i] = o;
    }
    return;
  }
  const int m = blockIdx.x;
  const float4* xr = (const float4*)(x + (size_t)m * K_DIM);
  ushort4* xbr = (ushort4*)(xb + (size_t)m * K_DIM);
  float a[8] = {0.f,0.f,0.f,0.f,0.f,0.f,0.f,0.f};
  #pragma unroll
  for (int i = 0; i < 4; ++i) {
    const int k4 = t + i * 256;
    float4 v = xr[k4];
    ushort4 o;
    o.x = f2bf(v.x); o.y = f2bf(v.y); o.z = f2bf(v.z); o.w = f2bf(v.w);
    xbr[k4] = o;
    #pragma unroll
    for (int r = 0; r < 8; ++r) {
      float4 wv = ((const float4*)(WA + (size_t)r * K_DIM))[k4];
      a[r] += v.x * wv.x + v.y * wv.y + v.z * wv.z + v.w * wv.w;
    }
  }
  #pragma unroll
  for (int r = 0; r < 8; ++r) {
    #pragma unroll
    for (int off = 32; off > 0; off >>= 1)
      a[r] += __shfl_down(a[r], off);
  }
  __shared__ float red[4][8];
  const int w = t >> 6, l = t & 63;
  if (l == 0) {
    #pragma unroll
    for (int r = 0; r < 8; ++r) red[w][r] = a[r];
  }
  __syncthreads();
  if (t < 8)
    mid[(size_t)m * 8 + t] = 2.0f * (red[0][t] + red[1][t] + red[2][t] + red[3][t]);
}

// ---- main GEMM: 256x256 tile, BK=32, 8 waves (2Mx4N).
// R10: 2-DEEP LDS RING (64 KiB) -> TWO BLOCKS PER CU (16 waves, 4/SIMD).
//   R5/R8/R9 all pinned at ~2450 cyc/tile = MFMA(1242) + LDS(~1200)
//   serialized: at 128 KiB LDS only ONE block fits per CU, so each SIMD
//   holds 2 waves of the SAME barrier-locked block — when they wait on
//   lgkm/vmcnt/barrier the MFMA pipe idles.  With 64 KiB, two independent
//   blocks co-reside and drift out of phase: block B's MFMA covers block
//   A's LDS drain (m114 cross-block overlap).  Mid-tile read-ahead is
//   illegal at depth 2 (buf[kt+1] is being staged during kt), so the tile
//   body reverts to R5's minimal form.  __launch_bounds__(512,4) caps
//   VGPR at 128 (R5's identical body measured 124).
//
// Ledger (FIFO, 4 gld_lds/tile/wave), tile kt:
//   - issue stage(kt+1) into buf[(kt+1)&1] FIRST (max time in flight).
//     That buf was last read during kt-1; those ds_reads drained before
//     MFMA(kt-1), one barrier ago -> no read/write race.
//   - read frags(kt) from buf[kt&1]; MFMA.
//   - vmcnt(0): s(kt+1) retired (had the whole MFMA cluster in flight;
//     the co-resident block covers the residual drain).
//   - barrier -> kt+1 reads are safe.
//   Prologue: stage tile 0; vmcnt(0); barrier.  Tail kt=127: no stage.
__global__ __launch_bounds__(512, 4) void k_gemm(
    const u16* __restrict__ A, const u16* __restrict__ B,
    const float* __restrict__ bias, const int* __restrict__ mask,
    const float* __restrict__ mid, const float* __restrict__ WBw,
    float* __restrict__ out) {
  __shared__ u16 smem[2][2][256][BK];   // [buf][A=0/B=1][row][k] = 64 KiB

  const int t = threadIdx.x;
  const int wid = t >> 6, l = t & 63;
  const int wr = wid >> 2, wc = wid & 3;   // 2x4 wave grid -> 128x64 out/wave
  const int fr = l & 15, fq = l >> 4;

  // T1: XCD-aware swizzle (512 blocks, 512%8==0 -> bijective)
  const int bid = blockIdx.x;
  const int swz = (bid & 7) * 64 + (bid >> 3);
  const int bm = swz >> 4, bn = swz & 15;

  const char* Ag = (const char*)(A + (size_t)bm * 256 * K_DIM);
  const char* Bg = (const char*)(B + (size_t)bn * 256 * K_DIM);
  const size_t rowb = (size_t)K_DIM * 2;

  // staging: q in {A-lo, A-hi, B-lo, B-hi}; 512 thr x 16B = 8KB per q.
  // thread t covers row t>>2; source 16B-chunk is the T2 pre-swizzle
  // (t&3)^((t>>3)&3) (4-lane groups stay within one 64B row-segment).
  const int srow = t >> 2;
  const int schk = (((t & 3) ^ ((t >> 3) & 3)) * 16);
  const char* gA0 = Ag + (size_t)srow * rowb + schk;
  const char* gA1 = Ag + (size_t)(128 + srow) * rowb + schk;
  const char* gB0 = Bg + (size_t)srow * rowb + schk;
  const char* gB1 = Bg + (size_t)(128 + srow) * rowb + schk;
  char* lbase = (char*)&smem[0][0][0][0] + wid * 1024;

  f32x4 acc[8][4];
  #pragma unroll
  for (int m = 0; m < 8; ++m)
    #pragma unroll
    for (int n = 0; n < 4; ++n)
      acc[m][n] = (f32x4){0.f, 0.f, 0.f, 0.f};

  // prologue: tile 0 into buf 0
  gld_lds16(gA0, lbase);
  gld_lds16(gA1, lbase + 8192);
  gld_lds16(gB0, lbase + 16384);
  gld_lds16(gB1, lbase + 24576);
  asm volatile("s_waitcnt vmcnt(0)" ::: "memory");
  __builtin_amdgcn_s_barrier();

  // T2 read-side swizzled column (u16 units), wave-invariant
  const int csw = (fq ^ ((fr >> 1) & 3)) * 8;

  // One K32-tile: stage-issue first, then frag reads + MFMA, vmcnt(0),
  // barrier.  BUFC/NB literal 0/1; GOFF = byte offset of the STAGED tile
  // (kt+1) relative to the running pointers.
  #define K_TILE(BUFC, NB, DOSTAGE, GOFF, DOWAIT) do {                       \
    if (DOSTAGE) {                                                           \
      gld_lds16(gA0 + (GOFF), lbase + (NB) * 32768);                         \
      gld_lds16(gA1 + (GOFF), lbase + (NB) * 32768 + 8192);                  \
      gld_lds16(gB0 + (GOFF), lbase + (NB) * 32768 + 16384);                 \
      gld_lds16(gB1 + (GOFF), lbase + (NB) * 32768 + 24576);                 \
    }                                                                        \
    {                                                                        \
      const u16* Ab_ = &smem[BUFC][0][wr * 128 + fr][csw];                   \
      const u16* Bb_ = &smem[BUFC][1][wc * 64 + fr][csw];                    \
      bf16x8 af_[8], bf_[4];                                                 \
      _Pragma("unroll")                                                      \
      for (int m = 0; m < 8; ++m)                                            \
        af_[m] = *(const bf16x8*)(Ab_ + m * 16 * BK);                        \
      _Pragma("unroll")                                                      \
      for (int n = 0; n < 4; ++n)                                            \
        bf_[n] = *(const bf16x8*)(Bb_ + n * 16 * BK);                        \
      __builtin_amdgcn_s_setprio(1);                                         \
      _Pragma("unroll")                                                      \
      for (int m = 0; m < 8; ++m)                                            \
        _Pragma("unroll")                                                    \
        for (int n = 0; n < 4; ++n)                                          \
          acc[m][n] = __builtin_amdgcn_mfma_f32_16x16x32_bf16(               \
              af_[m], bf_[n], acc[m][n], 0, 0, 0);                           \
      __builtin_amdgcn_s_setprio(0);                                         \
    }                                                                        \
    if (DOWAIT) {                                                            \
      asm volatile("s_waitcnt vmcnt(0)" ::: "memory");                       \
      __builtin_amdgcn_s_barrier();                                          \
    }                                                                        \
  } while (0)

  // steady: 63 pairs (kt = 0..125), stage kt+1 each tile
  for (int ktb = 0; ktb < NKT - 2; ktb += 2) {
    K_TILE(0, 1, true, 64,  true);   // kt even: stage kt+1 -> buf1
    K_TILE(1, 0, true, 128, true);   // kt odd : stage kt+2 -> buf0
    gA0 += 128; gA1 += 128; gB0 += 128; gB1 += 128;
  }
  // peeled tail: kt = 126 (stage 127 -> buf1), kt = 127 (no stage/wait)
  K_TILE(0, 1, true,  64, true);
  K_TILE(1, 0, false, 0,  false);

  #undef K_TILE

  // ---- epilogue: bias + masked rank-8 LoRA, fp32 out ----
  const int gn0 = bn * 256 + wc * 64;
  const size_t gm0 = (size_t)bm * 256 + wr * 128;
  float wbv[4][8]; float bv[4];
  #pragma unroll
  for (int n = 0; n < 4; ++n) {
    const int gn = gn0 + n * 16 + fr;
    bv[n] = bias[gn];
    const float4 w0 = ((const float4*)(WBw + (size_t)gn * 8))[0];
    const float4 w1 = ((const float4*)(WBw + (size_t)gn * 8))[1];
    wbv[n][0] = w0.x; wbv[n][1] = w0.y; wbv[n][2] = w0.z; wbv[n][3] = w0.w;
    wbv[n][4] = w1.x; wbv[n][5] = w1.y; wbv[n][6] = w1.z; wbv[n][7] = w1.w;
  }
  #pragma unroll
  for (int m = 0; m < 8; ++m) {
    #pragma unroll
    for (int j = 0; j < 4; ++j) {
      const size_t gm = gm0 + m * 16 + fq * 4 + j;   // C/D row = (l>>4)*4+reg
      const int msk = mask[gm];
      const float4 m0 = ((const float4*)(mid + gm * 8))[0];
      const float4 m1 = ((const float4*)(mid + gm * 8))[1];
      float* orow = out + gm * (size_t)N_DIM;
      #pragma unroll
      for (int n = 0; n < 4; ++n) {
        const float lora =
            m0.x * wbv[n][0] + m0.y * wbv[n][1] + m0.z * wbv[n][2] + m0.w * wbv[n][3] +
            m1.x * wbv[n][4] + m1.y * wbv[n][5] + m1.z * wbv[n][6] + m1.w * wbv[n][7];
        orow[gn0 + n * 16 + fr] = acc[m][n][j] + bv[n] + (msk ? lora : 0.0f);
      }
    }
  }
}

extern "C" void kernel_launch(void* const* d_in, const int* in_sizes, int n_in,
                              void* d_out, int out_size, void* d_ws, size_t ws_size,
                              hipStream_t stream) {
  (void)in_sizes; (void)n_in; (void)out_size; (void)ws_size;
  const float* x     = (const float*)d_in[0];
  const int*   mask  = (const int*)d_in[1];
  const float* Wm    = (const float*)d_in[2];
  const float* bmain = (const float*)d_in[3];
  const float* WA    = (const float*)d_in[4];
  const float* WB    = (const float*)d_in[5];
  float* out = (float*)d_out;

  u16* xb  = (u16*)d_ws;                                // 64 MiB
  u16* wb  = xb + (size_t)M_TOK * K_DIM;                // 32 MiB
  float* mid = (float*)(wb + (size_t)N_DIM * K_DIM);    // 256 KiB

  k_prep<<<M_TOK + 2048, 256, 0, stream>>>(x, WA, Wm, xb, mid, wb);
  dim3 grid((M_TOK / 256) * (N_DIM / 256));             // 512 blocks
  k_gemm<<<grid, 512, 0, stream>>>(xb, wb, bmain, mask, mid, WB, out);
}

// Round 11
// 349.204 us; speedup vs baseline: 8.8774x; 8.8774x over previous
//
#include <hip/hip_runtime.h>

typedef unsigned short u16;
typedef unsigned int   u32;
typedef unsigned long long u64;
typedef __bf16 bf16x8 __attribute__((ext_vector_type(8)));
typedef float  f32x4  __attribute__((ext_vector_type(4)));

#define AS1 __attribute__((address_space(1)))
#define AS3 __attribute__((address_space(3)))

#define M_TOK 8192
#define K_DIM 4096
#define N_DIM 4096
#define BK    32
#define NKT   (K_DIM / BK)   // 128

static __device__ __forceinline__ u16 f2bf(float f) {
  u32 u = __builtin_bit_cast(u32, f);
  return (u16)((u + (0x7FFFu + ((u >> 16) & 1u))) >> 16);
}

// global -> LDS direct copy, 16B per lane. LDS dest is wave-uniform base;
// HW stores lane l at dest + l*16 (linear, rule #21).
static __device__ __forceinline__ void gld_lds16(const void* g, void* l) {
  __builtin_amdgcn_global_load_lds((AS1 u32*)(u64)g, (AS3 u32*)(u32)(u64)l, 16, 0, 0);
}

// ---- fused prep: blocks [0, M_TOK) do per-token x->bf16 + LoRA mid;
//      blocks [M_TOK, M_TOK+2048) convert W_main f32->bf16 (grid-stride). ----
__global__ __launch_bounds__(256) void k_prep(const float* __restrict__ x,
                                              const float* __restrict__ WA,
                                              const float* __restrict__ W,
                                              u16* __restrict__ xb,
                                              float* __restrict__ mid,
                                              u16* __restrict__ Wb) {
  const int t = threadIdx.x;
  if (blockIdx.x >= M_TOK) {
    const int cb = blockIdx.x - M_TOK;           // 0..2047
    const float4* W4 = (const float4*)W;
    ushort4* Wb4 = (ushort4*)Wb;
    const int n4 = (N_DIM * K_DIM) / 4;
    int i = cb * 256 + t;
    for (; i < n4; i += 2048 * 256) {
      float4 v = W4[i];
      ushort4 o;
      o.x = f2bf(v.x); o.y = f2bf(v.y); o.z = f2bf(v.z); o.w = f2bf(v.w);
      Wb4[i] = o;
    }
    return;
  }
  const int m = blockIdx.x;
  const float4* xr = (const float4*)(x + (size_t)m * K_DIM);
  ushort4* xbr = (ushort4*)(xb + (size_t)m * K_DIM);
  float a[8] = {0.f,0.f,0.f,0.f,0.f,0.f,0.f,0.f};
  #pragma unroll
  for (int i = 0; i < 4; ++i) {
    const int k4 = t + i * 256;
    float4 v = xr[k4];
    ushort4 o;
    o.x = f2bf(v.x); o.y = f2bf(v.y); o.z = f2bf(v.z); o.w = f2bf(v.w);
    xbr[k4] = o;
    #pragma unroll
    for (int r = 0; r < 8; ++r) {
      float4 wv = ((const float4*)(WA + (size_t)r * K_DIM))[k4];
      a[r] += v.x * wv.x + v.y * wv.y + v.z * wv.z + v.w * wv.w;
    }
  }
  #pragma unroll
  for (int r = 0; r < 8; ++r) {
    #pragma unroll
    for (int off = 32; off > 0; off >>= 1)
      a[r] += __shfl_down(a[r], off);
  }
  __shared__ float red[4][8];
  const int w = t >> 6, l = t & 63;
  if (l == 0) {
    #pragma unroll
    for (int r = 0; r < 8; ++r) red[w][r] = a[r];
  }
  __syncthreads();
  if (t < 8)
    mid[(size_t)m * 8 + t] = 2.0f * (red[0][t] + red[1][t] + red[2][t] + red[3][t]);
}

// ---- main GEMM: 256x256 tile, BK=32, 8 waves (2Mx4N).
// R11: 2-DEEP LDS RING (64 KiB) with __launch_bounds__(512,2).
//   R10's theory (2 blocks/CU so cross-block wave drift covers the LDS
//   drain) was right; its implementation was wrong: min-waves=4 forced the
//   allocator to the 64-VGPR quantum and acc[8][4]=128 f32 spilled
//   (WRITE_SIZE 8.9 GB, MfmaUtil 3.7%).  Correct config: keep (512,2)
//   (always compiled to 124-128 VGPR) and let LDS gate occupancy:
//   2 blocks x 64 KiB = 128 <= 160 KiB, 16 waves/CU = 4 waves/SIMD x 128
//   VGPR = exactly the 512-reg pool (m69 quanta).  Nothing forced.
//
// Ledger (FIFO, 4 gld_lds/tile/wave), tile kt:
//   - issue stage(kt+1) into buf[(kt+1)&1] FIRST (max time in flight).
//     That buf was last read during kt-1; those ds_reads drained before
//     MFMA(kt-1), one barrier ago -> no read/write race.
//   - read frags(kt) from buf[kt&1]; MFMA.
//   - vmcnt(0): s(kt+1) retired (whole MFMA cluster was in flight; the
//     co-resident block covers the residual drain).
//   - barrier -> kt+1 reads safe.
//   Prologue: stage tile 0; vmcnt(0); barrier.  Tail kt=127: no stage.
__global__ __launch_bounds__(512, 2) void k_gemm(
    const u16* __restrict__ A, const u16* __restrict__ B,
    const float* __restrict__ bias, const int* __restrict__ mask,
    const float* __restrict__ mid, const float* __restrict__ WBw,
    float* __restrict__ out) {
  __shared__ u16 smem[2][2][256][BK];   // [buf][A=0/B=1][row][k] = 64 KiB

  const int t = threadIdx.x;
  const int wid = t >> 6, l = t & 63;
  const int wr = wid >> 2, wc = wid & 3;   // 2x4 wave grid -> 128x64 out/wave
  const int fr = l & 15, fq = l >> 4;

  // T1: XCD-aware swizzle (512 blocks, 512%8==0 -> bijective)
  const int bid = blockIdx.x;
  const int swz = (bid & 7) * 64 + (bid >> 3);
  const int bm = swz >> 4, bn = swz & 15;

  const char* Ag = (const char*)(A + (size_t)bm * 256 * K_DIM);
  const char* Bg = (const char*)(B + (size_t)bn * 256 * K_DIM);
  const size_t rowb = (size_t)K_DIM * 2;

  // staging: q in {A-lo, A-hi, B-lo, B-hi}; 512 thr x 16B = 8KB per q.
  // thread t covers row t>>2; source 16B-chunk is the T2 pre-swizzle
  // (t&3)^((t>>3)&3) (4-lane groups stay within one 64B row-segment).
  const int srow = t >> 2;
  const int schk = (((t & 3) ^ ((t >> 3) & 3)) * 16);
  const char* gA0 = Ag + (size_t)srow * rowb + schk;
  const char* gA1 = Ag + (size_t)(128 + srow) * rowb + schk;
  const char* gB0 = Bg + (size_t)srow * rowb + schk;
  const char* gB1 = Bg + (size_t)(128 + srow) * rowb + schk;
  char* lbase = (char*)&smem[0][0][0][0] + wid * 1024;

  f32x4 acc[8][4];
  #pragma unroll
  for (int m = 0; m < 8; ++m)
    #pragma unroll
    for (int n = 0; n < 4; ++n)
      acc[m][n] = (f32x4){0.f, 0.f, 0.f, 0.f};

  // prologue: tile 0 into buf 0
  gld_lds16(gA0, lbase);
  gld_lds16(gA1, lbase + 8192);
  gld_lds16(gB0, lbase + 16384);
  gld_lds16(gB1, lbase + 24576);
  asm volatile("s_waitcnt vmcnt(0)" ::: "memory");
  __builtin_amdgcn_s_barrier();

  // T2 read-side swizzled column (u16 units), wave-invariant
  const int csw = (fq ^ ((fr >> 1) & 3)) * 8;

  // One K32-tile: stage-issue first, then frag reads + MFMA, vmcnt(0),
  // barrier.  BUFC/NB literal 0/1; GOFF = byte offset of the STAGED tile
  // (kt+1) relative to the running pointers.
  #define K_TILE(BUFC, NB, DOSTAGE, GOFF, DOWAIT) do {                       \
    if (DOSTAGE) {                                                           \
      gld_lds16(gA0 + (GOFF), lbase + (NB) * 32768);                         \
      gld_lds16(gA1 + (GOFF), lbase + (NB) * 32768 + 8192);                  \
      gld_lds16(gB0 + (GOFF), lbase + (NB) * 32768 + 16384);                 \
      gld_lds16(gB1 + (GOFF), lbase + (NB) * 32768 + 24576);                 \
    }                                                                        \
    {                                                                        \
      const u16* Ab_ = &smem[BUFC][0][wr * 128 + fr][csw];                   \
      const u16* Bb_ = &smem[BUFC][1][wc * 64 + fr][csw];                    \
      bf16x8 af_[8], bf_[4];                                                 \
      _Pragma("unroll")                                                      \
      for (int m = 0; m < 8; ++m)                                            \
        af_[m] = *(const bf16x8*)(Ab_ + m * 16 * BK);                        \
      _Pragma("unroll")                                                      \
      for (int n = 0; n < 4; ++n)                                            \
        bf_[n] = *(const bf16x8*)(Bb_ + n * 16 * BK);                        \
      __builtin_amdgcn_s_setprio(1);                                         \
      _Pragma("unroll")                                                      \
      for (int m = 0; m < 8; ++m)                                            \
        _Pragma("unroll")                                                    \
        for (int n = 0; n < 4; ++n)                                          \
          acc[m][n] = __builtin_amdgcn_mfma_f32_16x16x32_bf16(               \
              af_[m], bf_[n], acc[m][n], 0, 0, 0);                           \
      __builtin_amdgcn_s_setprio(0);                                         \
    }                                                                        \
    if (DOWAIT) {                                                            \
      asm volatile("s_waitcnt vmcnt(0)" ::: "memory");                       \
      __builtin_amdgcn_s_barrier();                                          \
    }                                                                        \
  } while (0)

  // steady: 63 pairs (kt = 0..125), stage kt+1 each tile
  for (int ktb = 0; ktb < NKT - 2; ktb += 2) {
    K_TILE(0, 1, true, 64,  true);   // kt even: stage kt+1 -> buf1
    K_TILE(1, 0, true, 128, true);   // kt odd : stage kt+2 -> buf0
    gA0 += 128; gA1 += 128; gB0 += 128; gB1 += 128;
  }
  // peeled tail: kt = 126 (stage 127 -> buf1), kt = 127 (no stage/wait)
  K_TILE(0, 1, true,  64, true);
  K_TILE(1, 0, false, 0,  false);

  #undef K_TILE

  // ---- epilogue: bias + masked rank-8 LoRA, fp32 out ----
  const int gn0 = bn * 256 + wc * 64;
  const size_t gm0 = (size_t)bm * 256 + wr * 128;
  float wbv[4][8]; float bv[4];
  #pragma unroll
  for (int n = 0; n < 4; ++n) {
    const int gn = gn0 + n * 16 + fr;
    bv[n] = bias[gn];
    const float4 w0 = ((const float4*)(WBw + (size_t)gn * 8))[0];
    const float4 w1 = ((const float4*)(WBw + (size_t)gn * 8))[1];
    wbv[n][0] = w0.x; wbv[n][1] = w0.y; wbv[n][2] = w0.z; wbv[n][3] = w0.w;
    wbv[n][4] = w1.x; wbv[n][5] = w1.y; wbv[n][6] = w1.z; wbv[n][7] = w1.w;
  }
  #pragma unroll
  for (int m = 0; m < 8; ++m) {
    #pragma unroll
    for (int j = 0; j < 4; ++j) {
      const size_t gm = gm0 + m * 16 + fq * 4 + j;   // C/D row = (l>>4)*4+reg
      const int msk = mask[gm];
      const float4 m0 = ((const float4*)(mid + gm * 8))[0];
      const float4 m1 = ((const float4*)(mid + gm * 8))[1];
      float* orow = out + gm * (size_t)N_DIM;
      #pragma unroll
      for (int n = 0; n < 4; ++n) {
        const float lora =
            m0.x * wbv[n][0] + m0.y * wbv[n][1] + m0.z * wbv[n][2] + m0.w * wbv[n][3] +
            m1.x * wbv[n][4] + m1.y * wbv[n][5] + m1.z * wbv[n][6] + m1.w * wbv[n][7];
        orow[gn0 + n * 16 + fr] = acc[m][n][j] + bv[n] + (msk ? lora : 0.0f);
      }
    }
  }
}

extern "C" void kernel_launch(void* const* d_in, const int* in_sizes, int n_in,
                              void* d_out, int out_size, void* d_ws, size_t ws_size,
                              hipStream_t stream) {
  (void)in_sizes; (void)n_in; (void)out_size; (void)ws_size;
  const float* x     = (const float*)d_in[0];
  const int*   mask  = (const int*)d_in[1];
  const float* Wm    = (const float*)d_in[2];
  const float* bmain = (const float*)d_in[3];
  const float* WA    = (const float*)d_in[4];
  const float* WB    = (const float*)d_in[5];
  float* out = (float*)d_out;

  u16* xb  = (u16*)d_ws;                                // 64 MiB
  u16* wb  = xb + (size_t)M_TOK * K_DIM;                // 32 MiB
  float* mid = (float*)(wb + (size_t)N_DIM * K_DIM);    // 256 KiB

  k_prep<<<M_TOK + 2048, 256, 0, stream>>>(x, WA, Wm, xb, mid, wb);
  dim3 grid((M_TOK / 256) * (N_DIM / 256));             // 512 blocks
  k_gemm<<<grid, 512, 0, stream>>>(xb, wb, bmain, mask, mid, WB, out);
}

// Round 12
// 320.695 us; speedup vs baseline: 9.6666x; 1.0889x over previous
//
#include <hip/hip_runtime.h>

typedef unsigned short u16;
typedef unsigned int   u32;
typedef unsigned long long u64;
typedef __bf16 bf16x8 __attribute__((ext_vector_type(8)));
typedef float  f32x4  __attribute__((ext_vector_type(4)));

#define AS1 __attribute__((address_space(1)))
#define AS3 __attribute__((address_space(3)))

#define M_TOK 8192
#define K_DIM 4096
#define N_DIM 4096
#define BK    64
#define NKT   (K_DIM / BK)   // 64

static __device__ __forceinline__ u16 f2bf(float f) {
  u32 u = __builtin_bit_cast(u32, f);
  return (u16)((u + (0x7FFFu + ((u >> 16) & 1u))) >> 16);
}

// global -> LDS direct copy, 16B per lane. LDS dest is wave-uniform base;
// HW stores lane l at dest + l*16 (linear, rule #21).
static __device__ __forceinline__ void gld_lds16(const void* g, void* l) {
  __builtin_amdgcn_global_load_lds((AS1 u32*)(u64)g, (AS3 u32*)(u32)(u64)l, 16, 0, 0);
}

// ---- fused prep: blocks [0, M_TOK) do per-token x->bf16 + LoRA mid;
//      blocks [M_TOK, M_TOK+2048) convert W_main f32->bf16 (grid-stride). ----
__global__ __launch_bounds__(256) void k_prep(const float* __restrict__ x,
                                              const float* __restrict__ WA,
                                              const float* __restrict__ W,
                                              u16* __restrict__ xb,
                                              float* __restrict__ mid,
                                              u16* __restrict__ Wb) {
  const int t = threadIdx.x;
  if (blockIdx.x >= M_TOK) {
    const int cb = blockIdx.x - M_TOK;           // 0..2047
    const float4* W4 = (const float4*)W;
    ushort4* Wb4 = (ushort4*)Wb;
    const int n4 = (N_DIM * K_DIM) / 4;
    int i = cb * 256 + t;
    for (; i < n4; i += 2048 * 256) {
      float4 v = W4[i];
      ushort4 o;
      o.x = f2bf(v.x); o.y = f2bf(v.y); o.z = f2bf(v.z); o.w = f2bf(v.w);
      Wb4[i] = o;
    }
    return;
  }
  const int m = blockIdx.x;
  const float4* xr = (const float4*)(x + (size_t)m * K_DIM);
  ushort4* xbr = (ushort4*)(xb + (size_t)m * K_DIM);
  float a[8] = {0.f,0.f,0.f,0.f,0.f,0.f,0.f,0.f};
  #pragma unroll
  for (int i = 0; i < 4; ++i) {
    const int k4 = t + i * 256;
    float4 v = xr[k4];
    ushort4 o;
    o.x = f2bf(v.x); o.y = f2bf(v.y); o.z = f2bf(v.z); o.w = f2bf(v.w);
    xbr[k4] = o;
    #pragma unroll
    for (int r = 0; r < 8; ++r) {
      float4 wv = ((const float4*)(WA + (size_t)r * K_DIM))[k4];
      a[r] += v.x * wv.x + v.y * wv.y + v.z * wv.z + v.w * wv.w;
    }
  }
  #pragma unroll
  for (int r = 0; r < 8; ++r) {
    #pragma unroll
    for (int off = 32; off > 0; off >>= 1)
      a[r] += __shfl_down(a[r], off);
  }
  __shared__ float red[4][8];
  const int w = t >> 6, l = t & 63;
  if (l == 0) {
    #pragma unroll
    for (int r = 0; r < 8; ++r) red[w][r] = a[r];
  }
  __syncthreads();
  if (t < 8)
    mid[(size_t)m * 8 + t] = 2.0f * (red[0][t] + red[1][t] + red[2][t] + red[3][t]);
}

// ---- main GEMM: 256x256 tile, BK=64, 8 waves (2Mx4N), 2-dbuf (128 KiB).
// R12: faithful m201 8-phase port.  Per K64-tile, 4 phases; phase q:
//   {4 ds_read_b128 (A-frags of C-quadrant m=2q,2q+1; +8 B-frags at q0)
//    | 2 gld_lds (stage one group of tile kt+1)
//    -> barrier -> setprio(1) 16 MFMA setprio(0) -> [counted vmcnt] -> barrier}
// Fine clusters let early-draining waves' MFMA overlap late waves' LDS
// reads (m196: coarse clusters cost 7-27%; m201 = 1563-1728 TF @ 4k/8k).
//
// LDS: smem[2][2][256][64] (buf, A/B, row, col) = 128 KiB; 128B rows in
// 4 row-groups of 64 per operand; XOR swizzle slot' = slot ^ (row&7)
// (stage pre-swizzle (t&7)^((t>>3)&7); read slot (ks*4+fq)^(fr&7)) --
// bank-balanced: 8 lanes per slot-value across 4 banks = minimum 8 rounds.
//
// Stage order during tile kt (2 loads/phase, tile kt+1's data):
//   q0: B[0-64),B[64-128)   q1: B[128-192),B[192-256)
//   q2: A[0-64),A[128-192)  q3: A[64-128),A[192-256)
// Reads of tile kt: q0 needs B full + A grp0,2 (rows 0-31/128-159);
//   q1 needs A grp0,2 (rows 32-63/160-191); q2/q3 need A grp1,3.
// FIFO ledger (8 loads/tile/wave):
//   end q1: vmcnt(4)  (outstanding 6 -> retires kt-1.q3 pair = A grp1,3
//           of kt, needed by kt.q2)  [in flight >= 2 phases]
//   end q3: vmcnt(2)  (retires B full + A grp0,2 of kt+1; leaves kt.q3's
//           A grp1,3 pair)  [in flight >= 2 phases]
//   Tile 0: prologue stages tile 0 fully, vmcnt(0); q1's VM4/q3's VM2 are
//           then no-ops/early-retire -- safe.  Tile 63 (no stage): q1 end
//           VM0 (retire tile-62.q3 pair), q3 end none.
// Stage-overwrite safety: buf[kt+1]=buf[kt-1]; B of buf[kt-1] last read
// at kt-1.q0 (B lives in regs per tile); A grp0,2 last read kt-1.q1;
// A grp1,3 last read kt-1.q3 -- all >=2 barriers before their restage.
__global__ __launch_bounds__(512, 2) void k_gemm(
    const u16* __restrict__ A, const u16* __restrict__ B,
    const float* __restrict__ bias, const int* __restrict__ mask,
    const float* __restrict__ mid, const float* __restrict__ WBw,
    float* __restrict__ out) {
  __shared__ u16 smem[2][2][256][64];   // 128 KiB
  char* lds = (char*)&smem[0][0][0][0];

  const int t = threadIdx.x;
  const int wid = t >> 6, l = t & 63;
  const int wr = wid >> 2, wc = wid & 3;   // 2x4 wave grid -> 128x64 out/wave
  const int fr = l & 15, fq = l >> 4;

  // T1: XCD-aware swizzle (512 blocks, 512%8==0 -> bijective)
  const int bid = blockIdx.x;
  const int swz = (bid & 7) * 64 + (bid >> 3);
  const int bm = swz >> 4, bn = swz & 15;

  const char* Ag = (const char*)(A + (size_t)bm * 256 * K_DIM);
  const char* Bg = (const char*)(B + (size_t)bn * 256 * K_DIM);
  const size_t rowb = (size_t)K_DIM * 2;   // 8192 B

  // staging: thread t covers row-in-group t>>3 (0..63), source 16B chunk
  // (t&7)^((t>>3)&7) of the 128B row segment (coalesced per 8-lane group).
  const int srow8 = t >> 3;
  const int schk = (((t & 7) ^ ((t >> 3) & 7)) * 16);
  const char* sA0 = Ag + (size_t)(  0 + srow8) * rowb + schk;
  const char* sA1 = Ag + (size_t)( 64 + srow8) * rowb + schk;
  const char* sA2 = Ag + (size_t)(128 + srow8) * rowb + schk;
  const char* sA3 = Ag + (size_t)(192 + srow8) * rowb + schk;
  const char* sB0 = Bg + (size_t)(  0 + srow8) * rowb + schk;
  const char* sB1 = Bg + (size_t)( 64 + srow8) * rowb + schk;
  const char* sB2 = Bg + (size_t)(128 + srow8) * rowb + schk;
  const char* sB3 = Bg + (size_t)(192 + srow8) * rowb + schk;
  const int widoff = wid * 1024;

  // read-side: per-lane swizzled slot offsets for ks=0,1 and frag bases
  const int so0 = ((fq) ^ (fr & 7)) * 16;
  const int so1 = ((4 + fq) ^ (fr & 7)) * 16;
  const int aoff = (wr * 128 + fr) * 128;            // within A half
  const int boff = 32768 + (wc * 64 + fr) * 128;     // within buffer

  f32x4 acc[8][4];
  #pragma unroll
  for (int m = 0; m < 8; ++m)
    #pragma unroll
    for (int n = 0; n < 4; ++n)
      acc[m][n] = (f32x4){0.f, 0.f, 0.f, 0.f};

  // prologue: stage tile 0 -> buf0 (all 8 groups), drain, barrier
  gld_lds16(sB0, lds + 32768 +     0 + widoff);
  gld_lds16(sB1, lds + 32768 +  8192 + widoff);
  gld_lds16(sB2, lds + 32768 + 16384 + widoff);
  gld_lds16(sB3, lds + 32768 + 24576 + widoff);
  gld_lds16(sA0, lds +     0 + widoff);
  gld_lds16(sA2, lds + 16384 + widoff);
  gld_lds16(sA1, lds +  8192 + widoff);
  gld_lds16(sA3, lds + 24576 + widoff);
  asm volatile("s_waitcnt vmcnt(0)" ::: "memory");
  __builtin_amdgcn_s_barrier();

  bf16x8 bq[8];   // B frags [n][ks], loaded once per tile (phase 0)

  #define VM4 asm volatile("s_waitcnt vmcnt(4)" ::: "memory")
  #define VM2 asm volatile("s_waitcnt vmcnt(2)" ::: "memory")
  #define VM0 asm volatile("s_waitcnt vmcnt(0)" ::: "memory")
  #define NOW ((void)0)

  // Phase Q of a tile in buffer BUF. Stages into buf BUF^1 (literal).
  // S0/S1 global group ptrs; D0/D1 LDS region offsets; GOFF tile byte off.
  #define PHASE(BUF, Q, LOADB, DOSTAGE, S0, S1, D0, D1, GOFF, WAIT) do {     \
    const char* Ab_ = lds + (BUF) * 65536 + aoff;                            \
    bf16x8 a0_ = *(const bf16x8*)(Ab_ + (2*(Q)) * 2048 + so0);               \
    bf16x8 a1_ = *(const bf16x8*)(Ab_ + (2*(Q)) * 2048 + so1);               \
    bf16x8 a2_ = *(const bf16x8*)(Ab_ + (2*(Q)+1) * 2048 + so0);             \
    bf16x8 a3_ = *(const bf16x8*)(Ab_ + (2*(Q)+1) * 2048 + so1);             \
    if (LOADB) {                                                             \
      const char* Bb_ = lds + (BUF) * 65536 + boff;                          \
      _Pragma("unroll")                                                      \
      for (int n = 0; n < 4; ++n) {                                          \
        bq[2*n]   = *(const bf16x8*)(Bb_ + n * 2048 + so0);                  \
        bq[2*n+1] = *(const bf16x8*)(Bb_ + n * 2048 + so1);                  \
      }                                                                      \
    }                                                                        \
    if (DOSTAGE) {                                                           \
      gld_lds16((S0) + (GOFF), lds + ((BUF)^1) * 65536 + (D0) + widoff);     \
      gld_lds16((S1) + (GOFF), lds + ((BUF)^1) * 65536 + (D1) + widoff);     \
    }                                                                        \
    __builtin_amdgcn_sched_barrier(0);                                       \
    __builtin_amdgcn_s_barrier();                                            \
    __builtin_amdgcn_s_setprio(1);                                           \
    _Pragma("unroll")                                                        \
    for (int n = 0; n < 4; ++n) {                                            \
      acc[2*(Q)][n]   = __builtin_amdgcn_mfma_f32_16x16x32_bf16(             \
          a0_, bq[2*n],   acc[2*(Q)][n],   0, 0, 0);                         \
      acc[2*(Q)][n]   = __builtin_amdgcn_mfma_f32_16x16x32_bf16(             \
          a1_, bq[2*n+1], acc[2*(Q)][n],   0, 0, 0);                         \
      acc[2*(Q)+1][n] = __builtin_amdgcn_mfma_f32_16x16x32_bf16(             \
          a2_, bq[2*n],   acc[2*(Q)+1][n], 0, 0, 0);                         \
      acc[2*(Q)+1][n] = __builtin_amdgcn_mfma_f32_16x16x32_bf16(             \
          a3_, bq[2*n+1], acc[2*(Q)+1][n], 0, 0, 0);                         \
    }                                                                        \
    __builtin_amdgcn_s_setprio(0);                                           \
    WAIT;                                                                    \
    __builtin_amdgcn_s_barrier();                                            \
  } while (0)

  // one K64-tile: 4 phases with the stagger {B01, B23, A02, A13}
  #define K_TILE(BUF, DOSTAGE, GOFF, W1, W3)                                 \
    PHASE(BUF, 0, true,  DOSTAGE, sB0, sB1, 32768+0,     32768+8192,  GOFF, NOW); \
    PHASE(BUF, 1, false, DOSTAGE, sB2, sB3, 32768+16384, 32768+24576, GOFF, W1);  \
    PHASE(BUF, 2, false, DOSTAGE, sA0, sA2, 0,           16384,       GOFF, NOW); \
    PHASE(BUF, 3, false, DOSTAGE, sA1, sA3, 8192,        24576,       GOFF, W3)

  // steady: 31 iters x 2 tiles (tiles 0..61)
  for (int it = 0; it < 31; ++it) {
    K_TILE(0, true, 128, VM4, VM2);
    K_TILE(1, true, 256, VM4, VM2);
    sA0 += 256; sA1 += 256; sA2 += 256; sA3 += 256;
    sB0 += 256; sB1 += 256; sB2 += 256; sB3 += 256;
  }
  // tile 62 (buf0): stages tile 63 (GOFF 128)
  K_TILE(0, true, 128, VM4, VM2);
  // tile 63 (buf1): no staging; q1 end VM0 retires tile-62.q3 pair
  K_TILE(1, false, 0, VM0, NOW);

  #undef K_TILE
  #undef PHASE
  #undef VM4
  #undef VM2
  #undef VM0
  #undef NOW

  // ---- epilogue: bias + masked rank-8 LoRA, fp32 out ----
  const int gn0 = bn * 256 + wc * 64;
  const size_t gm0 = (size_t)bm * 256 + wr * 128;
  float wbv[4][8]; float bv[4];
  #pragma unroll
  for (int n = 0; n < 4; ++n) {
    const int gn = gn0 + n * 16 + fr;
    bv[n] = bias[gn];
    const float4 w0 = ((const float4*)(WBw + (size_t)gn * 8))[0];
    const float4 w1 = ((const float4*)(WBw + (size_t)gn * 8))[1];
    wbv[n][0] = w0.x; wbv[n][1] = w0.y; wbv[n][2] = w0.z; wbv[n][3] = w0.w;
    wbv[n][4] = w1.x; wbv[n][5] = w1.y; wbv[n][6] = w1.z; wbv[n][7] = w1.w;
  }
  #pragma unroll
  for (int m = 0; m < 8; ++m) {
    #pragma unroll
    for (int j = 0; j < 4; ++j) {
      const size_t gm = gm0 + m * 16 + fq * 4 + j;   // C/D row = (l>>4)*4+reg
      const int msk = mask[gm];
      const float4 m0 = ((const float4*)(mid + gm * 8))[0];
      const float4 m1 = ((const float4*)(mid + gm * 8))[1];
      float* orow = out + gm * (size_t)N_DIM;
      #pragma unroll
      for (int n = 0; n < 4; ++n) {
        const float lora =
            m0.x * wbv[n][0] + m0.y * wbv[n][1] + m0.z * wbv[n][2] + m0.w * wbv[n][3] +
            m1.x * wbv[n][4] + m1.y * wbv[n][5] + m1.z * wbv[n][6] + m1.w * wbv[n][7];
        orow[gn0 + n * 16 + fr] = acc[m][n][j] + bv[n] + (msk ? lora : 0.0f);
      }
    }
  }
}

extern "C" void kernel_launch(void* const* d_in, const int* in_sizes, int n_in,
                              void* d_out, int out_size, void* d_ws, size_t ws_size,
                              hipStream_t stream) {
  (void)in_sizes; (void)n_in; (void)out_size; (void)ws_size;
  const float* x     = (const float*)d_in[0];
  const int*   mask  = (const int*)d_in[1];
  const float* Wm    = (const float*)d_in[2];
  const float* bmain = (const float*)d_in[3];
  const float* WA    = (const float*)d_in[4];
  const float* WB    = (const float*)d_in[5];
  float* out = (float*)d_out;

  u16* xb  = (u16*)d_ws;                                // 64 MiB
  u16* wb  = xb + (size_t)M_TOK * K_DIM;                // 32 MiB
  float* mid = (float*)(wb + (size_t)N_DIM * K_DIM);    // 256 KiB

  k_prep<<<M_TOK + 2048, 256, 0, stream>>>(x, WA, Wm, xb, mid, wb);
  dim3 grid((M_TOK / 256) * (N_DIM / 256));             // 512 blocks
  k_gemm<<<grid, 512, 0, stream>>>(xb, wb, bmain, mask, mid, WB, out);
}